// Round 13
// baseline (443.167 us; speedup 1.0000x reference)
//
#include <hip/hip_runtime.h>
#include <stdint.h>

// Problem constants: B=8, H=256, W=256, C=16, HID=128, steps=2
#define BB 8
#define HH 256
#define WW 256
#define CC 16
#define HID 128
#define NPIX (BB*HH*WW)     // 524288
#define MTILE 64            // pixels per tile
#define NTILE (NPIX/MTILE)  // 8192
#define NBLKS 1024          // step grid: 4 blocks/CU, stable co-residency
#define TPT   (NTILE/NBLKS) // 8 tiles per block

typedef _Float16 h8 __attribute__((ext_vector_type(8)));
typedef __fp16   fp16v2 __attribute__((ext_vector_type(2)));   // cvt_pkrtz return type
typedef float    f4 __attribute__((ext_vector_type(4)));

// ---- LDS layout (dwords), 8192 dw = 32 KB exactly -> 5 blocks/CU.
// Epoch 1 (perception/GEMM1 reads): Ypk hi/mid planes + alpha-halo/life + FIRE.
// Epoch 2 (post-GEMM1): Hs[px 64][hid 128 ^ swz(px)] f32 = 8192 dw (full union).
// ctr lives in REGISTERS; fire is read back to a register (pinned) before epoch 2.
#define YPK_HI     0        // [64 px][52] u32: 3328 dw
#define YPK_MID    3328     // 3328..6655
#define ALPHA5_OFF 6656     // [5][68] f32 alpha halo = 340 dw
#define LIFE_OFF   6996     // [3][66] f32 life plane = 198 dw (ends 7193)
#define FIRE_OFF   7194     // [64] f32 fire mask (staging epoch only)
#define HS_OFF     0        // epoch 2: [64][128] f32
#define LDS_DW     8192     // 32768 B

// ---------------- Threefry2x32 (JAX-compatible, 20 rounds) ----------------
__host__ __device__ __forceinline__ uint32_t rotl32(uint32_t x, int r) {
  return (x << r) | (x >> (32 - r));
}

__host__ __device__ inline void threefry2x32(uint32_t k0, uint32_t k1,
                                             uint32_t x0, uint32_t x1,
                                             uint32_t& o0, uint32_t& o1) {
  const uint32_t ks2 = k0 ^ k1 ^ 0x1BD11BDAu;
  x0 += k0; x1 += k1;
#define TF_R4(a,b,c,d) \
  x0 += x1; x1 = rotl32(x1,(a)); x1 ^= x0; \
  x0 += x1; x1 = rotl32(x1,(b)); x1 ^= x0; \
  x0 += x1; x1 = rotl32(x1,(c)); x1 ^= x0; \
  x0 += x1; x1 = rotl32(x1,(d)); x1 ^= x0;
  TF_R4(13,15,26,6)   x0 += k1;  x1 += ks2 + 1u;
  TF_R4(17,29,16,24)  x0 += ks2; x1 += k0 + 2u;
  TF_R4(13,15,26,6)   x0 += k0;  x1 += k1 + 3u;
  TF_R4(17,29,16,24)  x0 += k1;  x1 += ks2 + 4u;
  TF_R4(13,15,26,6)   x0 += ks2; x1 += k0 + 5u;
#undef TF_R4
  o0 = x0; o1 = x1;
}

// ---- split-fp16 (RTZ form): a ~= hi + mid with |a-hi-mid| <= ~2^-21|a|.
// (passed R12 at absmax 0.015625; 6 VALU per pair)
__device__ __forceinline__ void split2(float a, float b, uint32_t& hi, uint32_t& mid) {
  union { fp16v2 h; uint32_t u; } ph, pm;
  ph.h = __builtin_amdgcn_cvt_pkrtz(a, b);           // v_cvt_pkrtz_f16_f32
  hi = ph.u;
  float ra = a - (float)ph.h[0];                     // exact residuals
  float rb = b - (float)ph.h[1];
  pm.h = __builtin_amdgcn_cvt_pkrtz(ra, rb);
  mid = pm.u;
}

// ---- W fragment precompute (once per launch; L2-resident afterwards) ------
// k-slot convention: GEMM1 k = 32*ks + 8*g + 2*r + h.
// GEMM2 khat = 2*g + 16*(r&1) + 8*h + (r>>1) (same bijection on A and B side).
__global__ __launch_bounds__(256)
void prep_frags(const float* __restrict__ W0g, const float* __restrict__ W1g,
                uint32_t* __restrict__ W0F, uint32_t* __restrict__ W1F) {
  const int tid = blockIdx.x * 256 + threadIdx.x;
  for (int idx = tid; idx < 6144; idx += gridDim.x * 256) {
    const int r = idx & 3, l = (idx >> 2) & 63, ks = (idx >> 8) % 3, n = idx / 768;
    const int g = l >> 4, c = l & 15;
    const int k0 = 32 * ks + 8 * g + 2 * r;
    const int hid = 16 * n + c;
    const float a = (k0     < 80) ? W0g[k0 * HID + hid]       : 0.f;
    const float b = (k0 + 1 < 80) ? W0g[(k0 + 1) * HID + hid] : 0.f;
    uint32_t hi, mid; split2(a, b, hi, mid);
    W0F[(size_t)(((n * 3 + ks) * 2 + 0) * 64 + l) * 4 + r] = hi;
    W0F[(size_t)(((n * 3 + ks) * 2 + 1) * 64 + l) * 4 + r] = mid;
  }
  for (int idx = tid; idx < 1024; idx += gridDim.x * 256) {
    const int r = idx & 3, l = (idx >> 2) & 63, ks = idx >> 8;
    const int g = l >> 4, c = l & 15;
    float va[2];
#pragma unroll
    for (int h = 0; h < 2; ++h) {
      const int khat = 2 * g + 16 * (r & 1) + 8 * h + (r >> 1);
      va[h] = W1g[(size_t)(32 * ks + khat) * CC + c];
    }
    uint32_t hi, mid; split2(va[0], va[1], hi, mid);
    W1F[(size_t)((ks * 2 + 0) * 64 + l) * 4 + r] = hi;
    W1F[(size_t)((ks * 2 + 1) * 64 + l) * 4 + r] = mid;
  }
}

// ---------------- Fused step kernel (MFMA, 8 tiles per block) --------------
// Per-tile body is verbatim R12 (passed, absmax 0.015625); outer loop over
// TPT=8 tiles with a tail barrier per tile (protects Hs reads from the next
// tile's staging — the dispatch boundary used to provide this).
// Block b, iter it -> tile = ((b&7)<<10)|((b>>3)<<3)|it: XCD b&7 owns one
// image; a block's 8 tiles = two adjacent image rows (halo L1/L2-warm).
template <int APPLY_LIFE>
__global__ __launch_bounds__(256, 5)
void step_fused(const float* __restrict__ xin,
                const uint32_t* __restrict__ W0F,
                const uint32_t* __restrict__ W1F,
                const float* __restrict__ b0g,
                const float* __restrict__ aPrev,
                const unsigned char* __restrict__ mPrev,
                float* __restrict__ xn,
                float* __restrict__ alpha_out,
                unsigned char* __restrict__ prelife,
                uint32_t k0, uint32_t k1) {
  __shared__ uint32_t LDSU[LDS_DW];
  float* const LDSF = (float*)LDSU;

  const int t    = threadIdx.x;
  const int lane = t & 63;
  const int w    = __builtin_amdgcn_readfirstlane(t >> 6);  // wave 0..3
  const int g    = lane >> 4;
  const int c15  = lane & 15;

  const float bv0 = b0g[16 * (2 * w + 0) + c15];
  const float bv1 = b0g[16 * (2 * w + 1) + c15];

  // W1^T A-frags: tile-invariant, hoisted out of the tile loop
  uint4 W1H[4], W1M[4];
#pragma unroll
  for (int ks = 0; ks < 4; ++ks) {
    W1H[ks] = *(const uint4*)(W1F + (size_t)((ks * 2 + 0) * 64 + lane) * 4);
    W1M[ks] = *(const uint4*)(W1F + (size_t)((ks * 2 + 1) * 64 + lane) * 4);
  }

  uint4 BH[2][2], BM[2][2];           // [ks parity][nl]
#define LOADB(par, kss) do { \
  _Pragma("unroll") for (int nl_ = 0; nl_ < 2; ++nl_) { \
    const int n_ = 2 * w + nl_; \
    BH[par][nl_] = *(const uint4*)(W0F + (size_t)(((n_ * 3 + (kss)) * 2 + 0) * 64 + lane) * 4); \
    BM[par][nl_] = *(const uint4*)(W0F + (size_t)(((n_ * 3 + (kss)) * 2 + 1) * 64 + lane) * 4); \
  } } while (0)

#pragma unroll 1
  for (int it = 0; it < TPT; ++it) {
    const int blk = ((blockIdx.x & 7) << 10) | ((blockIdx.x >> 3) << 3) | it;

    // -- phase 0: issue slab-0 B-frags early (latency under staging) --
    LOADB(0, 0);

    const int base_ = blk * MTILE;
    const int bi    = base_ >> 16;
    const int rc    = base_ & 0xFFFF;
    const int ic    = rc >> 8;
    const int jc0   = rc & 0xFF;        // multiple of 64

    // ---- inline life of previous step (compile-time gated) ----
    if constexpr (APPLY_LIFE) {
      const float* ap = aPrev + (size_t)bi * (HH * WW);
      for (int itr = t; itr < 340; itr += 256) {     // alpha halo 5 x 68
        const int r = itr / 68, c = itr - r * 68;
        const int ii = ic - 2 + r, jj = jc0 - 2 + c;
        float v = 0.f;
        if ((unsigned)ii < (unsigned)HH && (unsigned)jj < (unsigned)WW)
          v = ap[ii * WW + jj];
        LDSF[ALPHA5_OFF + itr] = v;
      }
      __syncthreads();
      if (t < 198) {                                  // life plane 3 x 66
        const int r = t / 66, xx = t - r * 66;
        const float* a0 = &LDSF[ALPHA5_OFF + r * 68 + xx];
        const float m0 = fmaxf(fmaxf(a0[0],   a0[1]),   a0[2]);
        const float m1 = fmaxf(fmaxf(a0[68],  a0[69]),  a0[70]);
        const float m2 = fmaxf(fmaxf(a0[136], a0[137]), a0[138]);
        const float mm = fmaxf(fmaxf(m0, m1), m2);
        const int ii = ic - 1 + r, jj = jc0 - 1 + xx;
        int pl = 0;
        if ((unsigned)ii < (unsigned)HH && (unsigned)jj < (unsigned)WW)
          pl = mPrev[(size_t)bi * (HH * WW) + ii * WW + jj];
        LDSF[LIFE_OFF + t] = (pl && mm > 0.1f) ? 1.0f : 0.0f;
      }
      __syncthreads();
    }

    // ---------------- perception: px = 16w + c15, quarter = g --------------
    const int px  = 16 * w + c15;
    const int c4  = 4 * g;
    const int gpx = base_ + px;
    const int jc  = jc0 + px;

    const float DXW[3][3] = {{-0.125f, 0.0f, 0.125f},
                             {-0.25f,  0.0f, 0.25f },
                             {-0.125f, 0.0f, 0.125f}};
    const float DYW[3][3] = {{-0.125f, -0.25f, -0.125f},
                             { 0.0f,    0.0f,   0.0f  },
                             { 0.125f,  0.25f,  0.125f}};
    const float LPW[3][3] = {{0.125f, 0.25f, 0.125f},
                             {0.25f, -1.5f,  0.25f },
                             {0.125f, 0.25f, 0.125f}};
    const float L2W[3][3] = {{0.0f,   0.125f, 0.0f  },
                             {0.125f, -0.5f,  0.125f},
                             {0.0f,   0.125f, 0.0f  }};

    float ctr[4] = {0,0,0,0};
    float adx[4] = {0,0,0,0};
    float ady[4] = {0,0,0,0};
    float alp[4] = {0,0,0,0};
    float al2[4] = {0,0,0,0};
    float amax = 0.0f;

    const float* xb = xin + (size_t)bi * (HH * WW * CC);
#pragma unroll
    for (int di = -1; di <= 1; ++di) {
#pragma unroll
      for (int dj = -1; dj <= 1; ++dj) {
        const int ii = ic + di, jj = jc + dj;
        const bool ok = ((unsigned)ii < (unsigned)HH) && ((unsigned)jj < (unsigned)WW);
        float4 p = make_float4(0.f, 0.f, 0.f, 0.f);
        if (ok) p = *(const float4*)(xb + ((size_t)(ii * WW + jj) * CC + c4));
        if constexpr (APPLY_LIFE) {
          const float lf = LDSF[LIFE_OFF + (di + 1) * 66 + (px + dj + 1)];
          p.x *= lf; p.y *= lf; p.z *= lf; p.w *= lf;
        }
        const float wdx = DXW[di+1][dj+1], wdy = DYW[di+1][dj+1];
        const float wlp = LPW[di+1][dj+1], wl2 = L2W[di+1][dj+1];
        const float pv[4] = {p.x, p.y, p.z, p.w};
#pragma unroll
        for (int q = 0; q < 4; ++q) {
          if (di == 0 && dj == 0) ctr[q] = pv[q];
          if (wdx != 0.f) adx[q] = fmaf(pv[q], wdx, adx[q]);
          if (wdy != 0.f) ady[q] = fmaf(pv[q], wdy, ady[q]);
          if (wlp != 0.f) alp[q] = fmaf(pv[q], wlp, alp[q]);
          if (wl2 != 0.f) al2[q] = fmaf(pv[q], wl2, al2[q]);
        }
        if (g == 0) amax = fmaxf(amax, p.w);   // channel 3 lives in quarter 0
      }
    }

    // fire: wave 0 computes all 64 pixels' threefry once per tile
    if (t < 64) {
      uint32_t lo, hi2;
      threefry2x32(k0, k1, 0u, (uint32_t)(base_ + t), lo, hi2);
      const uint32_t bits = lo ^ hi2;
      const float u = __uint_as_float((bits >> 9) | 0x3f800000u) - 1.0f;
      LDSF[FIRE_OFF + t] = (u > 0.5f) ? 1.0f : 0.0f;
    }

    // Ypk writes: packed f16x2 pairs, kk = 8*grp + 2g (+1). stride 52.
    {
      const int q2 = g << 1;
#define WRYPK(grp, A) do { \
      uint32_t h0_, m0_, h1_, m1_; \
      split2(A[0], A[1], h0_, m0_); split2(A[2], A[3], h1_, m1_); \
      const int kk_ = 8 * (grp) + q2; \
      *(uint2*)&LDSU[YPK_HI  + px * 52 + kk_] = make_uint2(h0_, h1_); \
      *(uint2*)&LDSU[YPK_MID + px * 52 + kk_] = make_uint2(m0_, m1_); \
    } while (0)
      WRYPK(0, ctr); WRYPK(1, adx); WRYPK(2, ady); WRYPK(3, alp); WRYPK(4, al2);
#undef WRYPK
    }
    // zero K-pad rows kk 40..47 (k 80..95), both planes
#pragma unroll
    for (int j = 0; j < 4; ++j) {
      const int pos = t * 4 + j;
      const int plane = pos >> 9, rem = pos & 511;
      LDSU[plane * 3328 + (rem >> 3) * 52 + 40 + (rem & 7)] = 0u;
    }
    if (g == 0) prelife[gpx] = (amax > 0.1f) ? 1 : 0;

    __syncthreads();

    // own fire into a register BEFORE epoch 2 (Hs) overlays the staging area.
    float fire01 = LDSF[FIRE_OFF + px];
    asm volatile("" : "+v"(fire01));

    // ------- GEMM1: D[px][hid] = Y @ W0, split-fp16 3-product MFMA --------
    f4 C1[4][2];
#pragma unroll
    for (int m = 0; m < 4; ++m) {
      C1[m][0] = (f4){bv0, bv0, bv0, bv0};
      C1[m][1] = (f4){bv1, bv1, bv1, bv1};
    }

    const int abase = c15 * 52 + 4 * g;
#pragma unroll
    for (int ks = 0; ks < 3; ++ks) {
      if (ks == 0) LOADB(1, 1);
      if (ks == 1) LOADB(0, 2);
      const int cur = ks & 1;
      __builtin_amdgcn_s_setprio(1);    // favor MFMA-issuing wave on the CU
#pragma unroll
      for (int m = 0; m < 4; ++m) {
        const uint4 uh = *(const uint4*)&LDSU[YPK_HI  + abase + m * 832 + 16 * ks];
        const uint4 um = *(const uint4*)&LDSU[YPK_MID + abase + m * 832 + 16 * ks];
        const h8 ah = __builtin_bit_cast(h8, uh);
        const h8 am = __builtin_bit_cast(h8, um);
#pragma unroll
        for (int nl = 0; nl < 2; ++nl) {
          const h8 bh = __builtin_bit_cast(h8, BH[cur][nl]);
          const h8 bm = __builtin_bit_cast(h8, BM[cur][nl]);
          C1[m][nl] = __builtin_amdgcn_mfma_f32_16x16x32_f16(ah, bh, C1[m][nl], 0, 0, 0);
          C1[m][nl] = __builtin_amdgcn_mfma_f32_16x16x32_f16(am, bh, C1[m][nl], 0, 0, 0);
          C1[m][nl] = __builtin_amdgcn_mfma_f32_16x16x32_f16(ah, bm, C1[m][nl], 0, 0, 0);
        }
      }
      __builtin_amdgcn_s_setprio(0);
    }

    __syncthreads();   // all Ypk/FIRE reads done before Hs overwrites the union

    // relu + h store, transposed+swizzled: Hs[px_w][hid ^ swz(px_w)]
    {
      const int sg = (g & 1) << 4;
      const int hid0 = 32 * w + c15;
      const int hid1 = hid0 + 16;
      const int hx00 = hid0 ^ sg,       hx01 = hid0 ^ (sg | 1);
      const int hx02 = hid0 ^ (sg | 8), hx03 = hid0 ^ (sg | 9);
      const int hx10 = hid1 ^ sg,       hx11 = hid1 ^ (sg | 1);
      const int hx12 = hid1 ^ (sg | 8), hx13 = hid1 ^ (sg | 9);
#pragma unroll
      for (int m = 0; m < 4; ++m) {
        const int rowb = (16 * m + 4 * g) * 128;
        {
          f4 hv = C1[m][0];
          LDSF[rowb +   0 + hx00] = fmaxf(hv.x, 0.f);
          LDSF[rowb + 128 + hx01] = fmaxf(hv.y, 0.f);
          LDSF[rowb + 256 + hx02] = fmaxf(hv.z, 0.f);
          LDSF[rowb + 384 + hx03] = fmaxf(hv.w, 0.f);
        }
        {
          f4 hv = C1[m][1];
          LDSF[rowb +   0 + hx10] = fmaxf(hv.x, 0.f);
          LDSF[rowb + 128 + hx11] = fmaxf(hv.y, 0.f);
          LDSF[rowb + 256 + hx12] = fmaxf(hv.z, 0.f);
          LDSF[rowb + 384 + hx13] = fmaxf(hv.w, 0.f);
        }
      }
    }

    __syncthreads();

    // ------- GEMM2: D[ch][px] = W1^T @ h^T (wave w: px-tile w) -------------
    f4 C2 = (f4){0.f, 0.f, 0.f, 0.f};
    {
      const int swzr  = (c15 & 1) | ((c15 & 6) << 2);
      const int hbase = px * 128 + 2 * g;
      int ka[4], kb[4];
#pragma unroll
      for (int r = 0; r < 4; ++r) {
        const int K0 = 16 * (r & 1) + (r >> 1);
        ka[r] = K0 ^ swzr;
        kb[r] = (K0 + 8) ^ swzr;
      }
#pragma unroll
      for (int ks = 0; ks < 4; ++ks) {
        uint32_t ph[4], pm[4];
#pragma unroll
        for (int r = 0; r < 4; ++r) {
          const float a = LDSF[hbase + 32 * ks + ka[r]];
          const float b = LDSF[hbase + 32 * ks + kb[r]];
          split2(a, b, ph[r], pm[r]);
        }
        const uint4 uh = make_uint4(ph[0], ph[1], ph[2], ph[3]);
        const uint4 um = make_uint4(pm[0], pm[1], pm[2], pm[3]);
        const h8 bh = __builtin_bit_cast(h8, uh);
        const h8 bm = __builtin_bit_cast(h8, um);
        const h8 ah = __builtin_bit_cast(h8, W1H[ks]);
        const h8 am = __builtin_bit_cast(h8, W1M[ks]);
        __builtin_amdgcn_s_setprio(1);
        C2 = __builtin_amdgcn_mfma_f32_16x16x32_f16(ah, bh, C2, 0, 0, 0);
        C2 = __builtin_amdgcn_mfma_f32_16x16x32_f16(am, bh, C2, 0, 0, 0);
        C2 = __builtin_amdgcn_mfma_f32_16x16x32_f16(ah, bm, C2, 0, 0, 0);
        __builtin_amdgcn_s_setprio(0);
      }
    }

    // ------- epilogue: all in registers ------------------------------------
    {
      f4 xv;
      xv.x = fmaf(C2.x, fire01, ctr[0]);
      xv.y = fmaf(C2.y, fire01, ctr[1]);
      xv.z = fmaf(C2.z, fire01, ctr[2]);
      xv.w = fmaf(C2.w, fire01, ctr[3]);
      *(f4*)&xn[(size_t)gpx * CC + c4] = xv;
      if (g == 0) alpha_out[gpx] = xv.w;   // channel 3
    }

    __syncthreads();   // protect Hs reads before next tile's staging writes
  }
#undef LOADB
}

// ---------------- Kernel B: final life mask, write-only-dead, in-place -----
__global__ __launch_bounds__(256)
void life_final(float* __restrict__ out,
                const float* __restrict__ alpha,
                const unsigned char* __restrict__ prelife) {
  // XCD swizzle (2048 blocks): XCD k gets one batch image's quarter-planes
  const int bswz = ((blockIdx.x & 7) << 8) | (blockIdx.x >> 3);
  const int idx = bswz * 256 + threadIdx.x;
  const int b  = idx >> 16;
  const int ij = idx & 0xFFFF;
  const int i  = ij >> 8;
  const int j  = ij & 0xFF;

  const float* ab = alpha + (size_t)b * (HH * WW);
  float amax = 0.0f;
#pragma unroll
  for (int di = -1; di <= 1; ++di) {
    const int ii = i + di;
    if ((unsigned)ii >= (unsigned)HH) continue;
#pragma unroll
    for (int dj = -1; dj <= 1; ++dj) {
      const int jj = j + dj;
      if ((unsigned)jj >= (unsigned)WW) continue;
      amax = fmaxf(amax, ab[(size_t)ii * WW + jj]);
    }
  }
  const bool life = (prelife[idx] != 0) && (amax > 0.1f);
  if (!life) {
    const float4 z = make_float4(0.0f, 0.0f, 0.0f, 0.0f);
    float4* dst = (float4*)(out + (size_t)idx * CC);
    dst[0] = z; dst[1] = z; dst[2] = z; dst[3] = z;
  }
}

// ---------------- Host launcher ----------------
extern "C" void kernel_launch(void* const* d_in, const int* in_sizes, int n_in,
                              void* d_out, int out_size, void* d_ws, size_t ws_size,
                              hipStream_t stream) {
  (void)in_sizes; (void)n_in; (void)out_size; (void)ws_size;
  const float* x  = (const float*)d_in[0];
  const float* W0 = (const float*)d_in[1];
  const float* b0 = (const float*)d_in[2];
  const float* W1 = (const float*)d_in[3];
  float* out = (float*)d_out;

  // Workspace: xn (32MB) | alphaA (2MB) | alphaB (2MB) | maskA | maskB | W0F | W1F
  float* xn = (float*)d_ws;
  float* alphaA = xn + (size_t)NPIX * CC;
  float* alphaB = alphaA + NPIX;
  unsigned char* maskA = (unsigned char*)(alphaB + NPIX);
  unsigned char* maskB = maskA + NPIX;
  uint32_t* W0F = (uint32_t*)(maskB + NPIX);
  uint32_t* W1F = W0F + 12288;

  prep_frags<<<128, 256, 0, stream>>>(W0, W1, W0F, W1F);

  uint32_t fk0, fk1;
  // step 0: raw input (no life), unmasked result -> xn, alpha/mask -> A
  threefry2x32(0u, 42u, 0u, 0u, fk0, fk1);
  step_fused<0><<<NBLKS, 256, 0, stream>>>(x, W0F, W1F, b0, nullptr, nullptr,
                                           xn, alphaA, maskA, fk0, fk1);
  // step 1: reads UNMASKED xn, applies step-0 life inline (alphaA/maskA)
  threefry2x32(0u, 42u, 0u, 1u, fk0, fk1);
  step_fused<1><<<NBLKS, 256, 0, stream>>>(xn, W0F, W1F, b0, alphaA, maskA,
                                           out, alphaB, maskB, fk0, fk1);
  // final masking: zero dead pixels of out in place
  life_final<<<NPIX / 256, 256, 0, stream>>>(out, alphaB, maskB);
}

// Round 14
// 427.154 us; speedup vs baseline: 1.0375x; 1.0375x over previous
//
#include <hip/hip_runtime.h>
#include <stdint.h>

// Problem constants: B=8, H=256, W=256, C=16, HID=128, steps=2
#define BB 8
#define HH 256
#define WW 256
#define CC 16
#define HID 128
#define NPIX (BB*HH*WW)     // 524288
#define MTILE 64            // pixels per tile
#define NTILE (NPIX/MTILE)  // 8192
#define NBLKS 1024          // step grid: 4 blocks/CU, stable co-residency
#define TPT   (NTILE/NBLKS) // 8 tiles per block

typedef _Float16 h8 __attribute__((ext_vector_type(8)));
typedef __fp16   fp16v2 __attribute__((ext_vector_type(2)));   // cvt_pkrtz return type
typedef float    f4 __attribute__((ext_vector_type(4)));

// ---- LDS layout (dwords), 8192 dw = 32 KB exactly -> 5 blocks/CU.
#define YPK_HI     0        // [64 px][52] u32: 3328 dw
#define YPK_MID    3328     // 3328..6655
#define ALPHA5_OFF 6656     // [5][68] f32 alpha halo = 340 dw
#define LIFE_OFF   6996     // [3][66] f32 life plane = 198 dw (ends 7193)
#define FIRE_OFF   7194     // [64] f32 fire mask (staging epoch only)
#define HS_OFF     0        // epoch 2: [64][128] f32
#define LDS_DW     8192     // 32768 B

// ---------------- Threefry2x32 (JAX-compatible, 20 rounds) ----------------
__host__ __device__ __forceinline__ uint32_t rotl32(uint32_t x, int r) {
  return (x << r) | (x >> (32 - r));
}

__host__ __device__ inline void threefry2x32(uint32_t k0, uint32_t k1,
                                             uint32_t x0, uint32_t x1,
                                             uint32_t& o0, uint32_t& o1) {
  const uint32_t ks2 = k0 ^ k1 ^ 0x1BD11BDAu;
  x0 += k0; x1 += k1;
#define TF_R4(a,b,c,d) \
  x0 += x1; x1 = rotl32(x1,(a)); x1 ^= x0; \
  x0 += x1; x1 = rotl32(x1,(b)); x1 ^= x0; \
  x0 += x1; x1 = rotl32(x1,(c)); x1 ^= x0; \
  x0 += x1; x1 = rotl32(x1,(d)); x1 ^= x0;
  TF_R4(13,15,26,6)   x0 += k1;  x1 += ks2 + 1u;
  TF_R4(17,29,16,24)  x0 += ks2; x1 += k0 + 2u;
  TF_R4(13,15,26,6)   x0 += k0;  x1 += k1 + 3u;
  TF_R4(17,29,16,24)  x0 += k1;  x1 += ks2 + 4u;
  TF_R4(13,15,26,6)   x0 += ks2; x1 += k0 + 5u;
#undef TF_R4
  o0 = x0; o1 = x1;
}

// ---- split-fp16 (RTZ form): a ~= hi + mid with |a-hi-mid| <= ~2^-21|a|.
// (passed R12/R13 at absmax 0.015625; 6 VALU per pair)
__device__ __forceinline__ void split2(float a, float b, uint32_t& hi, uint32_t& mid) {
  union { fp16v2 h; uint32_t u; } ph, pm;
  ph.h = __builtin_amdgcn_cvt_pkrtz(a, b);           // v_cvt_pkrtz_f16_f32
  hi = ph.u;
  float ra = a - (float)ph.h[0];                     // exact residuals
  float rb = b - (float)ph.h[1];
  pm.h = __builtin_amdgcn_cvt_pkrtz(ra, rb);
  mid = pm.u;
}

// ---- W fragment precompute (once per launch; L2-resident afterwards) ------
// k-slot convention: GEMM1 k = 32*ks + 8*g + 2*r + h.
// GEMM2 khat = 2*g + 16*(r&1) + 8*h + (r>>1) (same bijection on A and B side).
__global__ __launch_bounds__(256)
void prep_frags(const float* __restrict__ W0g, const float* __restrict__ W1g,
                uint32_t* __restrict__ W0F, uint32_t* __restrict__ W1F) {
  const int tid = blockIdx.x * 256 + threadIdx.x;
  for (int idx = tid; idx < 6144; idx += gridDim.x * 256) {
    const int r = idx & 3, l = (idx >> 2) & 63, ks = (idx >> 8) % 3, n = idx / 768;
    const int g = l >> 4, c = l & 15;
    const int k0 = 32 * ks + 8 * g + 2 * r;
    const int hid = 16 * n + c;
    const float a = (k0     < 80) ? W0g[k0 * HID + hid]       : 0.f;
    const float b = (k0 + 1 < 80) ? W0g[(k0 + 1) * HID + hid] : 0.f;
    uint32_t hi, mid; split2(a, b, hi, mid);
    W0F[(size_t)(((n * 3 + ks) * 2 + 0) * 64 + l) * 4 + r] = hi;
    W0F[(size_t)(((n * 3 + ks) * 2 + 1) * 64 + l) * 4 + r] = mid;
  }
  for (int idx = tid; idx < 1024; idx += gridDim.x * 256) {
    const int r = idx & 3, l = (idx >> 2) & 63, ks = idx >> 8;
    const int g = l >> 4, c = l & 15;
    float va[2];
#pragma unroll
    for (int h = 0; h < 2; ++h) {
      const int khat = 2 * g + 16 * (r & 1) + 8 * h + (r >> 1);
      va[h] = W1g[(size_t)(32 * ks + khat) * CC + c];
    }
    uint32_t hi, mid; split2(va[0], va[1], hi, mid);
    W1F[(size_t)((ks * 2 + 0) * 64 + l) * 4 + r] = hi;
    W1F[(size_t)((ks * 2 + 1) * 64 + l) * 4 + r] = mid;
  }
}

// ---------------- Fused step kernel (MFMA, 8 tiles per block) --------------
// Per-tile body verbatim R12 (passed). SLOT-MAJOR tile map (R13 lesson):
// tile = ((b&7)<<10) | (it<<7) | (b>>3). At loop slot it, XCD k's 128 blocks
// cover one contiguous 32-row band (0.5 MB) of image k, sliding down as it
// advances -> halos are L2-local, working set << 4MB L2. R13's block-major
// map spread concurrent blocks over the whole image: 455MB FETCH, 2.6x slower.
template <int APPLY_LIFE>
__global__ __launch_bounds__(256, 5)
void step_fused(const float* __restrict__ xin,
                const uint32_t* __restrict__ W0F,
                const uint32_t* __restrict__ W1F,
                const float* __restrict__ b0g,
                const float* __restrict__ aPrev,
                const unsigned char* __restrict__ mPrev,
                float* __restrict__ xn,
                float* __restrict__ alpha_out,
                unsigned char* __restrict__ prelife,
                uint32_t k0, uint32_t k1) {
  __shared__ uint32_t LDSU[LDS_DW];
  float* const LDSF = (float*)LDSU;

  const int t    = threadIdx.x;
  const int lane = t & 63;
  const int w    = __builtin_amdgcn_readfirstlane(t >> 6);  // wave 0..3
  const int g    = lane >> 4;
  const int c15  = lane & 15;

  const float bv0 = b0g[16 * (2 * w + 0) + c15];
  const float bv1 = b0g[16 * (2 * w + 1) + c15];

  // W1^T A-frags: tile-invariant, hoisted out of the tile loop
  uint4 W1H[4], W1M[4];
#pragma unroll
  for (int ks = 0; ks < 4; ++ks) {
    W1H[ks] = *(const uint4*)(W1F + (size_t)((ks * 2 + 0) * 64 + lane) * 4);
    W1M[ks] = *(const uint4*)(W1F + (size_t)((ks * 2 + 1) * 64 + lane) * 4);
  }

  uint4 BH[2][2], BM[2][2];           // [ks parity][nl]
#define LOADB(par, kss) do { \
  _Pragma("unroll") for (int nl_ = 0; nl_ < 2; ++nl_) { \
    const int n_ = 2 * w + nl_; \
    BH[par][nl_] = *(const uint4*)(W0F + (size_t)(((n_ * 3 + (kss)) * 2 + 0) * 64 + lane) * 4); \
    BM[par][nl_] = *(const uint4*)(W0F + (size_t)(((n_ * 3 + (kss)) * 2 + 1) * 64 + lane) * 4); \
  } } while (0)

#pragma unroll 1
  for (int it = 0; it < TPT; ++it) {
    // SLOT-MAJOR map: concurrent blocks form a contiguous 32-row band.
    const int blk = ((blockIdx.x & 7) << 10) | (it << 7) | (blockIdx.x >> 3);

    // -- phase 0: issue slab-0 B-frags early (latency under staging) --
    LOADB(0, 0);

    const int base_ = blk * MTILE;
    const int bi    = base_ >> 16;
    const int rc    = base_ & 0xFFFF;
    const int ic    = rc >> 8;
    const int jc0   = rc & 0xFF;        // multiple of 64

    // ---- inline life of previous step (compile-time gated) ----
    if constexpr (APPLY_LIFE) {
      const float* ap = aPrev + (size_t)bi * (HH * WW);
      for (int itr = t; itr < 340; itr += 256) {     // alpha halo 5 x 68
        const int r = itr / 68, c = itr - r * 68;
        const int ii = ic - 2 + r, jj = jc0 - 2 + c;
        float v = 0.f;
        if ((unsigned)ii < (unsigned)HH && (unsigned)jj < (unsigned)WW)
          v = ap[ii * WW + jj];
        LDSF[ALPHA5_OFF + itr] = v;
      }
      __syncthreads();
      if (t < 198) {                                  // life plane 3 x 66
        const int r = t / 66, xx = t - r * 66;
        const float* a0 = &LDSF[ALPHA5_OFF + r * 68 + xx];
        const float m0 = fmaxf(fmaxf(a0[0],   a0[1]),   a0[2]);
        const float m1 = fmaxf(fmaxf(a0[68],  a0[69]),  a0[70]);
        const float m2 = fmaxf(fmaxf(a0[136], a0[137]), a0[138]);
        const float mm = fmaxf(fmaxf(m0, m1), m2);
        const int ii = ic - 1 + r, jj = jc0 - 1 + xx;
        int pl = 0;
        if ((unsigned)ii < (unsigned)HH && (unsigned)jj < (unsigned)WW)
          pl = mPrev[(size_t)bi * (HH * WW) + ii * WW + jj];
        LDSF[LIFE_OFF + t] = (pl && mm > 0.1f) ? 1.0f : 0.0f;
      }
      __syncthreads();
    }

    // ---------------- perception: px = 16w + c15, quarter = g --------------
    const int px  = 16 * w + c15;
    const int c4  = 4 * g;
    const int gpx = base_ + px;
    const int jc  = jc0 + px;

    const float DXW[3][3] = {{-0.125f, 0.0f, 0.125f},
                             {-0.25f,  0.0f, 0.25f },
                             {-0.125f, 0.0f, 0.125f}};
    const float DYW[3][3] = {{-0.125f, -0.25f, -0.125f},
                             { 0.0f,    0.0f,   0.0f  },
                             { 0.125f,  0.25f,  0.125f}};
    const float LPW[3][3] = {{0.125f, 0.25f, 0.125f},
                             {0.25f, -1.5f,  0.25f },
                             {0.125f, 0.25f, 0.125f}};
    const float L2W[3][3] = {{0.0f,   0.125f, 0.0f  },
                             {0.125f, -0.5f,  0.125f},
                             {0.0f,   0.125f, 0.0f  }};

    float ctr[4] = {0,0,0,0};
    float adx[4] = {0,0,0,0};
    float ady[4] = {0,0,0,0};
    float alp[4] = {0,0,0,0};
    float al2[4] = {0,0,0,0};
    float amax = 0.0f;

    const float* xb = xin + (size_t)bi * (HH * WW * CC);
#pragma unroll
    for (int di = -1; di <= 1; ++di) {
#pragma unroll
      for (int dj = -1; dj <= 1; ++dj) {
        const int ii = ic + di, jj = jc + dj;
        const bool ok = ((unsigned)ii < (unsigned)HH) && ((unsigned)jj < (unsigned)WW);
        float4 p = make_float4(0.f, 0.f, 0.f, 0.f);
        if (ok) p = *(const float4*)(xb + ((size_t)(ii * WW + jj) * CC + c4));
        if constexpr (APPLY_LIFE) {
          const float lf = LDSF[LIFE_OFF + (di + 1) * 66 + (px + dj + 1)];
          p.x *= lf; p.y *= lf; p.z *= lf; p.w *= lf;
        }
        const float wdx = DXW[di+1][dj+1], wdy = DYW[di+1][dj+1];
        const float wlp = LPW[di+1][dj+1], wl2 = L2W[di+1][dj+1];
        const float pv[4] = {p.x, p.y, p.z, p.w};
#pragma unroll
        for (int q = 0; q < 4; ++q) {
          if (di == 0 && dj == 0) ctr[q] = pv[q];
          if (wdx != 0.f) adx[q] = fmaf(pv[q], wdx, adx[q]);
          if (wdy != 0.f) ady[q] = fmaf(pv[q], wdy, ady[q]);
          if (wlp != 0.f) alp[q] = fmaf(pv[q], wlp, alp[q]);
          if (wl2 != 0.f) al2[q] = fmaf(pv[q], wl2, al2[q]);
        }
        if (g == 0) amax = fmaxf(amax, p.w);   // channel 3 lives in quarter 0
      }
    }

    // fire: wave 0 computes all 64 pixels' threefry once per tile
    if (t < 64) {
      uint32_t lo, hi2;
      threefry2x32(k0, k1, 0u, (uint32_t)(base_ + t), lo, hi2);
      const uint32_t bits = lo ^ hi2;
      const float u = __uint_as_float((bits >> 9) | 0x3f800000u) - 1.0f;
      LDSF[FIRE_OFF + t] = (u > 0.5f) ? 1.0f : 0.0f;
    }

    // Ypk writes: packed f16x2 pairs, kk = 8*grp + 2g (+1). stride 52.
    {
      const int q2 = g << 1;
#define WRYPK(grp, A) do { \
      uint32_t h0_, m0_, h1_, m1_; \
      split2(A[0], A[1], h0_, m0_); split2(A[2], A[3], h1_, m1_); \
      const int kk_ = 8 * (grp) + q2; \
      *(uint2*)&LDSU[YPK_HI  + px * 52 + kk_] = make_uint2(h0_, h1_); \
      *(uint2*)&LDSU[YPK_MID + px * 52 + kk_] = make_uint2(m0_, m1_); \
    } while (0)
      WRYPK(0, ctr); WRYPK(1, adx); WRYPK(2, ady); WRYPK(3, alp); WRYPK(4, al2);
#undef WRYPK
    }
    // zero K-pad rows kk 40..47 (k 80..95), both planes
#pragma unroll
    for (int j = 0; j < 4; ++j) {
      const int pos = t * 4 + j;
      const int plane = pos >> 9, rem = pos & 511;
      LDSU[plane * 3328 + (rem >> 3) * 52 + 40 + (rem & 7)] = 0u;
    }
    if (g == 0) prelife[gpx] = (amax > 0.1f) ? 1 : 0;

    __syncthreads();

    // own fire into a register BEFORE epoch 2 (Hs) overlays the staging area.
    float fire01 = LDSF[FIRE_OFF + px];
    asm volatile("" : "+v"(fire01));

    // ------- GEMM1: D[px][hid] = Y @ W0, split-fp16 3-product MFMA --------
    f4 C1[4][2];
#pragma unroll
    for (int m = 0; m < 4; ++m) {
      C1[m][0] = (f4){bv0, bv0, bv0, bv0};
      C1[m][1] = (f4){bv1, bv1, bv1, bv1};
    }

    const int abase = c15 * 52 + 4 * g;
#pragma unroll
    for (int ks = 0; ks < 3; ++ks) {
      if (ks == 0) LOADB(1, 1);
      if (ks == 1) LOADB(0, 2);
      const int cur = ks & 1;
      __builtin_amdgcn_s_setprio(1);    // favor MFMA-issuing wave on the CU
#pragma unroll
      for (int m = 0; m < 4; ++m) {
        const uint4 uh = *(const uint4*)&LDSU[YPK_HI  + abase + m * 832 + 16 * ks];
        const uint4 um = *(const uint4*)&LDSU[YPK_MID + abase + m * 832 + 16 * ks];
        const h8 ah = __builtin_bit_cast(h8, uh);
        const h8 am = __builtin_bit_cast(h8, um);
#pragma unroll
        for (int nl = 0; nl < 2; ++nl) {
          const h8 bh = __builtin_bit_cast(h8, BH[cur][nl]);
          const h8 bm = __builtin_bit_cast(h8, BM[cur][nl]);
          C1[m][nl] = __builtin_amdgcn_mfma_f32_16x16x32_f16(ah, bh, C1[m][nl], 0, 0, 0);
          C1[m][nl] = __builtin_amdgcn_mfma_f32_16x16x32_f16(am, bh, C1[m][nl], 0, 0, 0);
          C1[m][nl] = __builtin_amdgcn_mfma_f32_16x16x32_f16(ah, bm, C1[m][nl], 0, 0, 0);
        }
      }
      __builtin_amdgcn_s_setprio(0);
    }

    __syncthreads();   // all Ypk/FIRE reads done before Hs overwrites the union

    // relu + h store, transposed+swizzled: Hs[px_w][hid ^ swz(px_w)]
    {
      const int sg = (g & 1) << 4;
      const int hid0 = 32 * w + c15;
      const int hid1 = hid0 + 16;
      const int hx00 = hid0 ^ sg,       hx01 = hid0 ^ (sg | 1);
      const int hx02 = hid0 ^ (sg | 8), hx03 = hid0 ^ (sg | 9);
      const int hx10 = hid1 ^ sg,       hx11 = hid1 ^ (sg | 1);
      const int hx12 = hid1 ^ (sg | 8), hx13 = hid1 ^ (sg | 9);
#pragma unroll
      for (int m = 0; m < 4; ++m) {
        const int rowb = (16 * m + 4 * g) * 128;
        {
          f4 hv = C1[m][0];
          LDSF[rowb +   0 + hx00] = fmaxf(hv.x, 0.f);
          LDSF[rowb + 128 + hx01] = fmaxf(hv.y, 0.f);
          LDSF[rowb + 256 + hx02] = fmaxf(hv.z, 0.f);
          LDSF[rowb + 384 + hx03] = fmaxf(hv.w, 0.f);
        }
        {
          f4 hv = C1[m][1];
          LDSF[rowb +   0 + hx10] = fmaxf(hv.x, 0.f);
          LDSF[rowb + 128 + hx11] = fmaxf(hv.y, 0.f);
          LDSF[rowb + 256 + hx12] = fmaxf(hv.z, 0.f);
          LDSF[rowb + 384 + hx13] = fmaxf(hv.w, 0.f);
        }
      }
    }

    __syncthreads();

    // ------- GEMM2: D[ch][px] = W1^T @ h^T (wave w: px-tile w) -------------
    f4 C2 = (f4){0.f, 0.f, 0.f, 0.f};
    {
      const int swzr  = (c15 & 1) | ((c15 & 6) << 2);
      const int hbase = px * 128 + 2 * g;
      int ka[4], kb[4];
#pragma unroll
      for (int r = 0; r < 4; ++r) {
        const int K0 = 16 * (r & 1) + (r >> 1);
        ka[r] = K0 ^ swzr;
        kb[r] = (K0 + 8) ^ swzr;
      }
#pragma unroll
      for (int ks = 0; ks < 4; ++ks) {
        uint32_t ph[4], pm[4];
#pragma unroll
        for (int r = 0; r < 4; ++r) {
          const float a = LDSF[hbase + 32 * ks + ka[r]];
          const float b = LDSF[hbase + 32 * ks + kb[r]];
          split2(a, b, ph[r], pm[r]);
        }
        const uint4 uh = make_uint4(ph[0], ph[1], ph[2], ph[3]);
        const uint4 um = make_uint4(pm[0], pm[1], pm[2], pm[3]);
        const h8 bh = __builtin_bit_cast(h8, uh);
        const h8 bm = __builtin_bit_cast(h8, um);
        const h8 ah = __builtin_bit_cast(h8, W1H[ks]);
        const h8 am = __builtin_bit_cast(h8, W1M[ks]);
        __builtin_amdgcn_s_setprio(1);
        C2 = __builtin_amdgcn_mfma_f32_16x16x32_f16(ah, bh, C2, 0, 0, 0);
        C2 = __builtin_amdgcn_mfma_f32_16x16x32_f16(am, bh, C2, 0, 0, 0);
        C2 = __builtin_amdgcn_mfma_f32_16x16x32_f16(ah, bm, C2, 0, 0, 0);
        __builtin_amdgcn_s_setprio(0);
      }
    }

    // ------- epilogue: all in registers ------------------------------------
    {
      f4 xv;
      xv.x = fmaf(C2.x, fire01, ctr[0]);
      xv.y = fmaf(C2.y, fire01, ctr[1]);
      xv.z = fmaf(C2.z, fire01, ctr[2]);
      xv.w = fmaf(C2.w, fire01, ctr[3]);
      *(f4*)&xn[(size_t)gpx * CC + c4] = xv;
      if (g == 0) alpha_out[gpx] = xv.w;   // channel 3
    }

    __syncthreads();   // protect Hs reads before next tile's staging writes
  }
#undef LOADB
}

// ---------------- Kernel B: final life mask, write-only-dead, in-place -----
__global__ __launch_bounds__(256)
void life_final(float* __restrict__ out,
                const float* __restrict__ alpha,
                const unsigned char* __restrict__ prelife) {
  // XCD swizzle (2048 blocks): XCD k gets one batch image's quarter-planes
  const int bswz = ((blockIdx.x & 7) << 8) | (blockIdx.x >> 3);
  const int idx = bswz * 256 + threadIdx.x;
  const int b  = idx >> 16;
  const int ij = idx & 0xFFFF;
  const int i  = ij >> 8;
  const int j  = ij & 0xFF;

  const float* ab = alpha + (size_t)b * (HH * WW);
  float amax = 0.0f;
#pragma unroll
  for (int di = -1; di <= 1; ++di) {
    const int ii = i + di;
    if ((unsigned)ii >= (unsigned)HH) continue;
#pragma unroll
    for (int dj = -1; dj <= 1; ++dj) {
      const int jj = j + dj;
      if ((unsigned)jj >= (unsigned)WW) continue;
      amax = fmaxf(amax, ab[(size_t)ii * WW + jj]);
    }
  }
  const bool life = (prelife[idx] != 0) && (amax > 0.1f);
  if (!life) {
    const float4 z = make_float4(0.0f, 0.0f, 0.0f, 0.0f);
    float4* dst = (float4*)(out + (size_t)idx * CC);
    dst[0] = z; dst[1] = z; dst[2] = z; dst[3] = z;
  }
}

// ---------------- Host launcher ----------------
extern "C" void kernel_launch(void* const* d_in, const int* in_sizes, int n_in,
                              void* d_out, int out_size, void* d_ws, size_t ws_size,
                              hipStream_t stream) {
  (void)in_sizes; (void)n_in; (void)out_size; (void)ws_size;
  const float* x  = (const float*)d_in[0];
  const float* W0 = (const float*)d_in[1];
  const float* b0 = (const float*)d_in[2];
  const float* W1 = (const float*)d_in[3];
  float* out = (float*)d_out;

  // Workspace: xn (32MB) | alphaA (2MB) | alphaB (2MB) | maskA | maskB | W0F | W1F
  float* xn = (float*)d_ws;
  float* alphaA = xn + (size_t)NPIX * CC;
  float* alphaB = alphaA + NPIX;
  unsigned char* maskA = (unsigned char*)(alphaB + NPIX);
  unsigned char* maskB = maskA + NPIX;
  uint32_t* W0F = (uint32_t*)(maskB + NPIX);
  uint32_t* W1F = W0F + 12288;

  prep_frags<<<128, 256, 0, stream>>>(W0, W1, W0F, W1F);

  uint32_t fk0, fk1;
  // step 0: raw input (no life), unmasked result -> xn, alpha/mask -> A
  threefry2x32(0u, 42u, 0u, 0u, fk0, fk1);
  step_fused<0><<<NBLKS, 256, 0, stream>>>(x, W0F, W1F, b0, nullptr, nullptr,
                                           xn, alphaA, maskA, fk0, fk1);
  // step 1: reads UNMASKED xn, applies step-0 life inline (alphaA/maskA)
  threefry2x32(0u, 42u, 0u, 1u, fk0, fk1);
  step_fused<1><<<NBLKS, 256, 0, stream>>>(xn, W0F, W1F, b0, alphaA, maskA,
                                           out, alphaB, maskB, fk0, fk1);
  // final masking: zero dead pixels of out in place
  life_final<<<NPIX / 256, 256, 0, stream>>>(out, alphaB, maskB);
}

// Round 15
// 206.911 us; speedup vs baseline: 2.1418x; 2.0644x over previous
//
#include <hip/hip_runtime.h>
#include <stdint.h>

// Problem constants: B=8, H=256, W=256, C=16, HID=128, steps=2
#define BB 8
#define HH 256
#define WW 256
#define CC 16
#define HID 128
#define NPIX (BB*HH*WW)     // 524288
#define MTILE 64            // pixels per block
#define NBLK (NPIX/MTILE)   // 8192

typedef _Float16 h8 __attribute__((ext_vector_type(8)));
typedef __fp16   fp16v2 __attribute__((ext_vector_type(2)));   // cvt_pkrtz return type
typedef float    f4 __attribute__((ext_vector_type(4)));

// ---- LDS layout (dwords), 8192 dw = 32 KB exactly -> 5 blocks/CU.
// Epoch 1 (perception/GEMM1 reads): Ypk hi/mid planes + life + FIRE.
// Epoch 2 (post-GEMM1): Hs[px 64][hid 128 ^ swz(px)] f32 = 8192 dw (full union).
#define YPK_HI     0        // [64 px][52] u32: 3328 dw
#define YPK_MID    3328     // 3328..6655
#define LIFE_OFF   6996     // [3][66] f32 life plane = 198 dw
#define FIRE_OFF   7194     // [64] f32 fire mask (staging epoch only)
#define HS_OFF     0        // epoch 2: [64][128] f32
#define LDS_DW     8192     // 32768 B

// ---------------- Threefry2x32 (JAX-compatible, 20 rounds) ----------------
__host__ __device__ __forceinline__ uint32_t rotl32(uint32_t x, int r) {
  return (x << r) | (x >> (32 - r));
}

__host__ __device__ inline void threefry2x32(uint32_t k0, uint32_t k1,
                                             uint32_t x0, uint32_t x1,
                                             uint32_t& o0, uint32_t& o1) {
  const uint32_t ks2 = k0 ^ k1 ^ 0x1BD11BDAu;
  x0 += k0; x1 += k1;
#define TF_R4(a,b,c,d) \
  x0 += x1; x1 = rotl32(x1,(a)); x1 ^= x0; \
  x0 += x1; x1 = rotl32(x1,(b)); x1 ^= x0; \
  x0 += x1; x1 = rotl32(x1,(c)); x1 ^= x0; \
  x0 += x1; x1 = rotl32(x1,(d)); x1 ^= x0;
  TF_R4(13,15,26,6)   x0 += k1;  x1 += ks2 + 1u;
  TF_R4(17,29,16,24)  x0 += ks2; x1 += k0 + 2u;
  TF_R4(13,15,26,6)   x0 += k0;  x1 += k1 + 3u;
  TF_R4(17,29,16,24)  x0 += k1;  x1 += ks2 + 4u;
  TF_R4(13,15,26,6)   x0 += ks2; x1 += k0 + 5u;
#undef TF_R4
  o0 = x0; o1 = x1;
}

// ---- split-fp16 (RTZ form): a ~= hi + mid with |a-hi-mid| <= ~2^-21|a|.
// (passed R12/R13/R14 at absmax 0.015625; 6 VALU per pair)
__device__ __forceinline__ void split2(float a, float b, uint32_t& hi, uint32_t& mid) {
  union { fp16v2 h; uint32_t u; } ph, pm;
  ph.h = __builtin_amdgcn_cvt_pkrtz(a, b);           // v_cvt_pkrtz_f16_f32
  hi = ph.u;
  float ra = a - (float)ph.h[0];                     // exact residuals
  float rb = b - (float)ph.h[1];
  pm.h = __builtin_amdgcn_cvt_pkrtz(ra, rb);
  mid = pm.u;
}

// ---- W fragment precompute (once per launch; L2-resident afterwards) ------
// k-slot convention: GEMM1 k = 32*ks + 8*g + 2*r + h.
// GEMM2 khat = 2*g + 16*(r&1) + 8*h + (r>>1) (same bijection on A and B side).
__global__ __launch_bounds__(256)
void prep_frags(const float* __restrict__ W0g, const float* __restrict__ W1g,
                uint32_t* __restrict__ W0F, uint32_t* __restrict__ W1F) {
  const int tid = blockIdx.x * 256 + threadIdx.x;
  for (int idx = tid; idx < 6144; idx += gridDim.x * 256) {
    const int r = idx & 3, l = (idx >> 2) & 63, ks = (idx >> 8) % 3, n = idx / 768;
    const int g = l >> 4, c = l & 15;
    const int k0 = 32 * ks + 8 * g + 2 * r;
    const int hid = 16 * n + c;
    const float a = (k0     < 80) ? W0g[k0 * HID + hid]       : 0.f;
    const float b = (k0 + 1 < 80) ? W0g[(k0 + 1) * HID + hid] : 0.f;
    uint32_t hi, mid; split2(a, b, hi, mid);
    W0F[(size_t)(((n * 3 + ks) * 2 + 0) * 64 + l) * 4 + r] = hi;
    W0F[(size_t)(((n * 3 + ks) * 2 + 1) * 64 + l) * 4 + r] = mid;
  }
  for (int idx = tid; idx < 1024; idx += gridDim.x * 256) {
    const int r = idx & 3, l = (idx >> 2) & 63, ks = idx >> 8;
    const int g = l >> 4, c = l & 15;
    float va[2];
#pragma unroll
    for (int h = 0; h < 2; ++h) {
      const int khat = 2 * g + 16 * (r & 1) + 8 * h + (r >> 1);
      va[h] = W1g[(size_t)(32 * ks + khat) * CC + c];
    }
    uint32_t hi, mid; split2(va[0], va[1], hi, mid);
    W1F[(size_t)((ks * 2 + 0) * 64 + l) * 4 + r] = hi;
    W1F[(size_t)((ks * 2 + 1) * 64 + l) * 4 + r] = mid;
  }
}

// ---------------- Fused step kernel (MFMA) ----------------
// R12 structure (passed, 203.6 us): one tile per block, 8192 blocks, dispatch
// order = spatial order (the locality mechanism; persistent loops destroy it).
// Thread map: wave w, lane l: px = 16w + (l&15), quarter g = l>>4.
// Hs layout: [px][hid ^ swz(px)], swz(px) = (px&1) | ((px&6)<<2).
// XCD swizzle: blk = (bid&7)<<10 | bid>>3 (verified FETCH 39.7 -> 17.95 MB).
// R15 change vs R12: APPLY_LIFE computes the life plane DIRECTLY from global
// alpha (9 bounds-checked loads per life point; band is L2-hot) -- deletes
// the 5x68 alpha-halo LDS staging pass and one __syncthreads().
template <int APPLY_LIFE>
__global__ __launch_bounds__(256, 5)
void step_fused(const float* __restrict__ xin,
                const uint32_t* __restrict__ W0F,
                const uint32_t* __restrict__ W1F,
                const float* __restrict__ b0g,
                const float* __restrict__ aPrev,
                const unsigned char* __restrict__ mPrev,
                float* __restrict__ xn,
                float* __restrict__ alpha_out,
                unsigned char* __restrict__ prelife,
                uint32_t k0, uint32_t k1) {
  __shared__ uint32_t LDSU[LDS_DW];
  float* const LDSF = (float*)LDSU;

  const int t    = threadIdx.x;
  const int blk  = ((blockIdx.x & 7) << 10) | (blockIdx.x >> 3);  // XCD swizzle
  const int lane = t & 63;
  const int w    = __builtin_amdgcn_readfirstlane(t >> 6);  // wave 0..3
  const int g    = lane >> 4;
  const int c15  = lane & 15;

  // -- phase 0: issue slab-0 B-frags + bias early (latency under perception) --
  uint4 BH[2][2], BM[2][2];           // [ks parity][nl]
#pragma unroll
  for (int nl = 0; nl < 2; ++nl) {
    const int n = 2 * w + nl;
    BH[0][nl] = *(const uint4*)(W0F + (size_t)(((n * 3 + 0) * 2 + 0) * 64 + lane) * 4);
    BM[0][nl] = *(const uint4*)(W0F + (size_t)(((n * 3 + 0) * 2 + 1) * 64 + lane) * 4);
  }
  const float bv0 = b0g[16 * (2 * w + 0) + c15];
  const float bv1 = b0g[16 * (2 * w + 1) + c15];

  // Block geometry: 64 consecutive pixels = one row segment
  const int base_ = blk * MTILE;
  const int bi    = base_ >> 16;
  const int rc    = base_ & 0xFFFF;
  const int ic    = rc >> 8;
  const int jc0   = rc & 0xFF;        // multiple of 64

  // ---- inline life of previous step: DIRECT from global alpha ----
  if constexpr (APPLY_LIFE) {
    if (t < 198) {                                  // life plane 3 x 66
      const int r = t / 66, xx = t - r * 66;
      const int ii = ic - 1 + r, jj = jc0 - 1 + xx;
      const float* ap = aPrev + (size_t)bi * (HH * WW);
      float mm = 0.0f;                              // OOB alpha contributes 0
#pragma unroll
      for (int di = -1; di <= 1; ++di) {
#pragma unroll
        for (int dj = -1; dj <= 1; ++dj) {
          const int i2 = ii + di, j2 = jj + dj;
          if ((unsigned)i2 < (unsigned)HH && (unsigned)j2 < (unsigned)WW)
            mm = fmaxf(mm, ap[i2 * WW + j2]);
        }
      }
      int pl = 0;
      if ((unsigned)ii < (unsigned)HH && (unsigned)jj < (unsigned)WW)
        pl = mPrev[(size_t)bi * (HH * WW) + ii * WW + jj];
      LDSF[LIFE_OFF + t] = (pl && mm > 0.1f) ? 1.0f : 0.0f;
    }
    __syncthreads();
  }

  // ---------------- perception: px = 16w + c15, quarter = g ----------------
  const int px  = 16 * w + c15;
  const int c4  = 4 * g;
  const int gpx = base_ + px;
  const int jc  = jc0 + px;

  const float DXW[3][3] = {{-0.125f, 0.0f, 0.125f},
                           {-0.25f,  0.0f, 0.25f },
                           {-0.125f, 0.0f, 0.125f}};
  const float DYW[3][3] = {{-0.125f, -0.25f, -0.125f},
                           { 0.0f,    0.0f,   0.0f  },
                           { 0.125f,  0.25f,  0.125f}};
  const float LPW[3][3] = {{0.125f, 0.25f, 0.125f},
                           {0.25f, -1.5f,  0.25f },
                           {0.125f, 0.25f, 0.125f}};
  const float L2W[3][3] = {{0.0f,   0.125f, 0.0f  },
                           {0.125f, -0.5f,  0.125f},
                           {0.0f,   0.125f, 0.0f  }};

  float ctr[4] = {0,0,0,0};
  float adx[4] = {0,0,0,0};
  float ady[4] = {0,0,0,0};
  float alp[4] = {0,0,0,0};
  float al2[4] = {0,0,0,0};
  float amax = 0.0f;

  const float* xb = xin + (size_t)bi * (HH * WW * CC);
#pragma unroll
  for (int di = -1; di <= 1; ++di) {
#pragma unroll
    for (int dj = -1; dj <= 1; ++dj) {
      const int ii = ic + di, jj = jc + dj;
      const bool ok = ((unsigned)ii < (unsigned)HH) && ((unsigned)jj < (unsigned)WW);
      float4 p = make_float4(0.f, 0.f, 0.f, 0.f);
      if (ok) p = *(const float4*)(xb + ((size_t)(ii * WW + jj) * CC + c4));
      if constexpr (APPLY_LIFE) {
        const float lf = LDSF[LIFE_OFF + (di + 1) * 66 + (px + dj + 1)];
        p.x *= lf; p.y *= lf; p.z *= lf; p.w *= lf;
      }
      const float wdx = DXW[di+1][dj+1], wdy = DYW[di+1][dj+1];
      const float wlp = LPW[di+1][dj+1], wl2 = L2W[di+1][dj+1];
      const float pv[4] = {p.x, p.y, p.z, p.w};
#pragma unroll
      for (int q = 0; q < 4; ++q) {
        if (di == 0 && dj == 0) ctr[q] = pv[q];
        if (wdx != 0.f) adx[q] = fmaf(pv[q], wdx, adx[q]);
        if (wdy != 0.f) ady[q] = fmaf(pv[q], wdy, ady[q]);
        if (wlp != 0.f) alp[q] = fmaf(pv[q], wlp, alp[q]);
        if (wl2 != 0.f) al2[q] = fmaf(pv[q], wl2, al2[q]);
      }
      if (g == 0) amax = fmaxf(amax, p.w);   // channel 3 lives in quarter 0
    }
  }

  // fire: wave 0 computes all 64 pixels' threefry once (waves 1-3 skip the
  // whole ~100-instr chain via execz). Slot t holds fire for pixel base_+t.
  if (t < 64) {
    uint32_t lo, hi2;
    threefry2x32(k0, k1, 0u, (uint32_t)(base_ + t), lo, hi2);
    const uint32_t bits = lo ^ hi2;
    const float u = __uint_as_float((bits >> 9) | 0x3f800000u) - 1.0f;
    LDSF[FIRE_OFF + t] = (u > 0.5f) ? 1.0f : 0.0f;
  }

  // Ypk writes: packed f16x2 pairs, kk = 8*grp + 2g (+1). stride 52.
  {
    const int q2 = g << 1;
#define WRYPK(grp, A) do { \
    uint32_t h0_, m0_, h1_, m1_; \
    split2(A[0], A[1], h0_, m0_); split2(A[2], A[3], h1_, m1_); \
    const int kk_ = 8 * (grp) + q2; \
    *(uint2*)&LDSU[YPK_HI  + px * 52 + kk_] = make_uint2(h0_, h1_); \
    *(uint2*)&LDSU[YPK_MID + px * 52 + kk_] = make_uint2(m0_, m1_); \
  } while (0)
    WRYPK(0, ctr); WRYPK(1, adx); WRYPK(2, ady); WRYPK(3, alp); WRYPK(4, al2);
#undef WRYPK
  }
  // zero K-pad rows kk 40..47 (k 80..95), both planes
#pragma unroll
  for (int j = 0; j < 4; ++j) {
    const int pos = t * 4 + j;
    const int plane = pos >> 9, rem = pos & 511;
    LDSU[plane * 3328 + (rem >> 3) * 52 + 40 + (rem & 7)] = 0u;
  }
  if (g == 0) prelife[gpx] = (amax > 0.1f) ? 1 : 0;

  __syncthreads();

  // own fire into a register BEFORE epoch 2 (Hs) overlays the staging area.
  float fire01 = LDSF[FIRE_OFF + px];
  asm volatile("" : "+v"(fire01));

  // ------- GEMM1: D[px][hid] = Y @ W0, split-fp16 3-product MFMA ----------
  f4 C1[4][2];
#pragma unroll
  for (int m = 0; m < 4; ++m) {
    C1[m][0] = (f4){bv0, bv0, bv0, bv0};
    C1[m][1] = (f4){bv1, bv1, bv1, bv1};
  }

#define LOADB(par, kss) do { \
  _Pragma("unroll") for (int nl_ = 0; nl_ < 2; ++nl_) { \
    const int n_ = 2 * w + nl_; \
    BH[par][nl_] = *(const uint4*)(W0F + (size_t)(((n_ * 3 + (kss)) * 2 + 0) * 64 + lane) * 4); \
    BM[par][nl_] = *(const uint4*)(W0F + (size_t)(((n_ * 3 + (kss)) * 2 + 1) * 64 + lane) * 4); \
  } } while (0)

  const int abase = c15 * 52 + 4 * g;
#pragma unroll
  for (int ks = 0; ks < 3; ++ks) {
    if (ks == 0) LOADB(1, 1);
    if (ks == 1) LOADB(0, 2);
    const int cur = ks & 1;
    __builtin_amdgcn_s_setprio(1);      // favor MFMA-issuing wave on the CU
#pragma unroll
    for (int m = 0; m < 4; ++m) {
      const uint4 uh = *(const uint4*)&LDSU[YPK_HI  + abase + m * 832 + 16 * ks];
      const uint4 um = *(const uint4*)&LDSU[YPK_MID + abase + m * 832 + 16 * ks];
      const h8 ah = __builtin_bit_cast(h8, uh);
      const h8 am = __builtin_bit_cast(h8, um);
#pragma unroll
      for (int nl = 0; nl < 2; ++nl) {
        const h8 bh = __builtin_bit_cast(h8, BH[cur][nl]);
        const h8 bm = __builtin_bit_cast(h8, BM[cur][nl]);
        C1[m][nl] = __builtin_amdgcn_mfma_f32_16x16x32_f16(ah, bh, C1[m][nl], 0, 0, 0);
        C1[m][nl] = __builtin_amdgcn_mfma_f32_16x16x32_f16(am, bh, C1[m][nl], 0, 0, 0);
        C1[m][nl] = __builtin_amdgcn_mfma_f32_16x16x32_f16(ah, bm, C1[m][nl], 0, 0, 0);
      }
    }
    __builtin_amdgcn_s_setprio(0);
  }
#undef LOADB

  __syncthreads();   // all Ypk/FIRE reads done before Hs overwrites the union

  // relu + h store, transposed+swizzled: Hs[px_w][hid ^ swz(px_w)]
  // swz(px_w) = (j&1) | ((j&2)<<2) | ((g&1)<<4) for px_w = 16m+4g+j
  {
    const int sg = (g & 1) << 4;
    const int hid0 = 32 * w + c15;
    const int hid1 = hid0 + 16;
    const int hx00 = hid0 ^ sg,       hx01 = hid0 ^ (sg | 1);
    const int hx02 = hid0 ^ (sg | 8), hx03 = hid0 ^ (sg | 9);
    const int hx10 = hid1 ^ sg,       hx11 = hid1 ^ (sg | 1);
    const int hx12 = hid1 ^ (sg | 8), hx13 = hid1 ^ (sg | 9);
#pragma unroll
    for (int m = 0; m < 4; ++m) {
      const int rowb = (16 * m + 4 * g) * 128;
      {
        f4 hv = C1[m][0];
        LDSF[rowb +   0 + hx00] = fmaxf(hv.x, 0.f);
        LDSF[rowb + 128 + hx01] = fmaxf(hv.y, 0.f);
        LDSF[rowb + 256 + hx02] = fmaxf(hv.z, 0.f);
        LDSF[rowb + 384 + hx03] = fmaxf(hv.w, 0.f);
      }
      {
        f4 hv = C1[m][1];
        LDSF[rowb +   0 + hx10] = fmaxf(hv.x, 0.f);
        LDSF[rowb + 128 + hx11] = fmaxf(hv.y, 0.f);
        LDSF[rowb + 256 + hx12] = fmaxf(hv.z, 0.f);
        LDSF[rowb + 384 + hx13] = fmaxf(hv.w, 0.f);
      }
    }
  }

  // W1^T A-frags (latency covered by barrier)
  uint4 W1H[4], W1M[4];
#pragma unroll
  for (int ks = 0; ks < 4; ++ks) {
    W1H[ks] = *(const uint4*)(W1F + (size_t)((ks * 2 + 0) * 64 + lane) * 4);
    W1M[ks] = *(const uint4*)(W1F + (size_t)((ks * 2 + 1) * 64 + lane) * 4);
  }

  __syncthreads();

  // ------- GEMM2: D[ch][px] = W1^T @ h^T (wave w: px-tile w) ---------------
  f4 C2 = (f4){0.f, 0.f, 0.f, 0.f};
  {
    const int swzr  = (c15 & 1) | ((c15 & 6) << 2);
    const int hbase = px * 128 + 2 * g;
    int ka[4], kb[4];
#pragma unroll
    for (int r = 0; r < 4; ++r) {
      const int K0 = 16 * (r & 1) + (r >> 1);
      ka[r] = K0 ^ swzr;
      kb[r] = (K0 + 8) ^ swzr;
    }
#pragma unroll
    for (int ks = 0; ks < 4; ++ks) {
      uint32_t ph[4], pm[4];
#pragma unroll
      for (int r = 0; r < 4; ++r) {
        const float a = LDSF[hbase + 32 * ks + ka[r]];
        const float b = LDSF[hbase + 32 * ks + kb[r]];
        split2(a, b, ph[r], pm[r]);
      }
      const uint4 uh = make_uint4(ph[0], ph[1], ph[2], ph[3]);
      const uint4 um = make_uint4(pm[0], pm[1], pm[2], pm[3]);
      const h8 bh = __builtin_bit_cast(h8, uh);
      const h8 bm = __builtin_bit_cast(h8, um);
      const h8 ah = __builtin_bit_cast(h8, W1H[ks]);
      const h8 am = __builtin_bit_cast(h8, W1M[ks]);
      __builtin_amdgcn_s_setprio(1);
      C2 = __builtin_amdgcn_mfma_f32_16x16x32_f16(ah, bh, C2, 0, 0, 0);
      C2 = __builtin_amdgcn_mfma_f32_16x16x32_f16(am, bh, C2, 0, 0, 0);
      C2 = __builtin_amdgcn_mfma_f32_16x16x32_f16(ah, bm, C2, 0, 0, 0);
      __builtin_amdgcn_s_setprio(0);
    }
  }

  // ------- epilogue: all in registers (ctr, fire01 are this thread's own) --
  {
    f4 xv;
    xv.x = fmaf(C2.x, fire01, ctr[0]);
    xv.y = fmaf(C2.y, fire01, ctr[1]);
    xv.z = fmaf(C2.z, fire01, ctr[2]);
    xv.w = fmaf(C2.w, fire01, ctr[3]);
    *(f4*)&xn[(size_t)gpx * CC + c4] = xv;
    if (g == 0) alpha_out[gpx] = xv.w;   // channel 3
  }
}

// ---------------- Kernel B: final life mask, write-only-dead, in-place -----
__global__ __launch_bounds__(256)
void life_final(float* __restrict__ out,
                const float* __restrict__ alpha,
                const unsigned char* __restrict__ prelife) {
  // XCD swizzle (2048 blocks): XCD k gets one batch image's quarter-planes
  const int bswz = ((blockIdx.x & 7) << 8) | (blockIdx.x >> 3);
  const int idx = bswz * 256 + threadIdx.x;
  const int b  = idx >> 16;
  const int ij = idx & 0xFFFF;
  const int i  = ij >> 8;
  const int j  = ij & 0xFF;

  const float* ab = alpha + (size_t)b * (HH * WW);
  float amax = 0.0f;
#pragma unroll
  for (int di = -1; di <= 1; ++di) {
    const int ii = i + di;
    if ((unsigned)ii >= (unsigned)HH) continue;
#pragma unroll
    for (int dj = -1; dj <= 1; ++dj) {
      const int jj = j + dj;
      if ((unsigned)jj >= (unsigned)WW) continue;
      amax = fmaxf(amax, ab[(size_t)ii * WW + jj]);
    }
  }
  const bool life = (prelife[idx] != 0) && (amax > 0.1f);
  if (!life) {
    const float4 z = make_float4(0.0f, 0.0f, 0.0f, 0.0f);
    float4* dst = (float4*)(out + (size_t)idx * CC);
    dst[0] = z; dst[1] = z; dst[2] = z; dst[3] = z;
  }
}

// ---------------- Host launcher ----------------
extern "C" void kernel_launch(void* const* d_in, const int* in_sizes, int n_in,
                              void* d_out, int out_size, void* d_ws, size_t ws_size,
                              hipStream_t stream) {
  (void)in_sizes; (void)n_in; (void)out_size; (void)ws_size;
  const float* x  = (const float*)d_in[0];
  const float* W0 = (const float*)d_in[1];
  const float* b0 = (const float*)d_in[2];
  const float* W1 = (const float*)d_in[3];
  float* out = (float*)d_out;

  // Workspace: xn (32MB) | alphaA (2MB) | alphaB (2MB) | maskA | maskB | W0F | W1F
  float* xn = (float*)d_ws;
  float* alphaA = xn + (size_t)NPIX * CC;
  float* alphaB = alphaA + NPIX;
  unsigned char* maskA = (unsigned char*)(alphaB + NPIX);
  unsigned char* maskB = maskA + NPIX;
  uint32_t* W0F = (uint32_t*)(maskB + NPIX);
  uint32_t* W1F = W0F + 12288;

  prep_frags<<<128, 256, 0, stream>>>(W0, W1, W0F, W1F);

  uint32_t fk0, fk1;
  // step 0: raw input (no life), unmasked result -> xn, alpha/mask -> A
  threefry2x32(0u, 42u, 0u, 0u, fk0, fk1);
  step_fused<0><<<NBLK, 256, 0, stream>>>(x, W0F, W1F, b0, nullptr, nullptr,
                                          xn, alphaA, maskA, fk0, fk1);
  // step 1: reads UNMASKED xn, applies step-0 life inline (alphaA/maskA)
  threefry2x32(0u, 42u, 0u, 1u, fk0, fk1);
  step_fused<1><<<NBLK, 256, 0, stream>>>(xn, W0F, W1F, b0, alphaA, maskA,
                                          out, alphaB, maskB, fk0, fk1);
  // final masking: zero dead pixels of out in place
  life_final<<<NPIX / 256, 256, 0, stream>>>(out, alphaB, maskB);
}

// Round 16
// 203.139 us; speedup vs baseline: 2.1816x; 1.0186x over previous
//
#include <hip/hip_runtime.h>
#include <stdint.h>

// Problem constants: B=8, H=256, W=256, C=16, HID=128, steps=2
#define BB 8
#define HH 256
#define WW 256
#define CC 16
#define HID 128
#define NPIX (BB*HH*WW)     // 524288
#define MTILE 64            // pixels per block
#define NBLK (NPIX/MTILE)   // 8192

typedef _Float16 h8 __attribute__((ext_vector_type(8)));
typedef __fp16   fp16v2 __attribute__((ext_vector_type(2)));   // cvt_pkrtz return type
typedef float    f4 __attribute__((ext_vector_type(4)));

// ---- LDS layout (dwords), 8192 dw = 32 KB exactly -> 5 blocks/CU.
// Epoch 1 (perception/GEMM1 reads): Ypk hi/mid planes + alpha-halo/life + FIRE.
// Epoch 2 (post-GEMM1): Hs[px 64][hid 128 ^ swz(px)] f32 = 8192 dw (full union).
// ctr lives in REGISTERS; fire is read back to a register (pinned) before epoch 2.
#define YPK_HI     0        // [64 px][52] u32: 3328 dw
#define YPK_MID    3328     // 3328..6655
#define ALPHA5_OFF 6656     // [5][68] f32 alpha halo = 340 dw
#define LIFE_OFF   6996     // [3][66] f32 life plane = 198 dw (ends 7193)
#define FIRE_OFF   7194     // [64] f32 fire mask (staging epoch only)
#define HS_OFF     0        // epoch 2: [64][128] f32
#define LDS_DW     8192     // 32768 B

// ---------------- Threefry2x32 (JAX-compatible, 20 rounds) ----------------
__host__ __device__ __forceinline__ uint32_t rotl32(uint32_t x, int r) {
  return (x << r) | (x >> (32 - r));
}

__host__ __device__ inline void threefry2x32(uint32_t k0, uint32_t k1,
                                             uint32_t x0, uint32_t x1,
                                             uint32_t& o0, uint32_t& o1) {
  const uint32_t ks2 = k0 ^ k1 ^ 0x1BD11BDAu;
  x0 += k0; x1 += k1;
#define TF_R4(a,b,c,d) \
  x0 += x1; x1 = rotl32(x1,(a)); x1 ^= x0; \
  x0 += x1; x1 = rotl32(x1,(b)); x1 ^= x0; \
  x0 += x1; x1 = rotl32(x1,(c)); x1 ^= x0; \
  x0 += x1; x1 = rotl32(x1,(d)); x1 ^= x0;
  TF_R4(13,15,26,6)   x0 += k1;  x1 += ks2 + 1u;
  TF_R4(17,29,16,24)  x0 += ks2; x1 += k0 + 2u;
  TF_R4(13,15,26,6)   x0 += k0;  x1 += k1 + 3u;
  TF_R4(17,29,16,24)  x0 += k1;  x1 += ks2 + 4u;
  TF_R4(13,15,26,6)   x0 += ks2; x1 += k0 + 5u;
#undef TF_R4
  o0 = x0; o1 = x1;
}

// ---- split-fp16 (RTZ form): a ~= hi + mid with |a-hi-mid| <= ~2^-21|a|.
// hi = RTZ f16 (residual <= 2^-10|a|, exact f32 subtract), mid = RTZ of
// residual (error <= 2^-21|a|). 6 VALU per pair; passed R12-R15 at 0.015625.
__device__ __forceinline__ void split2(float a, float b, uint32_t& hi, uint32_t& mid) {
  union { fp16v2 h; uint32_t u; } ph, pm;
  ph.h = __builtin_amdgcn_cvt_pkrtz(a, b);           // v_cvt_pkrtz_f16_f32
  hi = ph.u;
  float ra = a - (float)ph.h[0];                     // exact residuals
  float rb = b - (float)ph.h[1];
  pm.h = __builtin_amdgcn_cvt_pkrtz(ra, rb);
  mid = pm.u;
}

// ---- W fragment precompute (once per launch; L2-resident afterwards) ------
// k-slot convention: GEMM1 k = 32*ks + 8*g + 2*r + h.
// GEMM2 khat = 2*g + 16*(r&1) + 8*h + (r>>1) (same bijection on A and B side).
__global__ __launch_bounds__(256)
void prep_frags(const float* __restrict__ W0g, const float* __restrict__ W1g,
                uint32_t* __restrict__ W0F, uint32_t* __restrict__ W1F) {
  const int tid = blockIdx.x * 256 + threadIdx.x;
  for (int idx = tid; idx < 6144; idx += gridDim.x * 256) {
    const int r = idx & 3, l = (idx >> 2) & 63, ks = (idx >> 8) % 3, n = idx / 768;
    const int g = l >> 4, c = l & 15;
    const int k0 = 32 * ks + 8 * g + 2 * r;
    const int hid = 16 * n + c;
    const float a = (k0     < 80) ? W0g[k0 * HID + hid]       : 0.f;
    const float b = (k0 + 1 < 80) ? W0g[(k0 + 1) * HID + hid] : 0.f;
    uint32_t hi, mid; split2(a, b, hi, mid);
    W0F[(size_t)(((n * 3 + ks) * 2 + 0) * 64 + l) * 4 + r] = hi;
    W0F[(size_t)(((n * 3 + ks) * 2 + 1) * 64 + l) * 4 + r] = mid;
  }
  for (int idx = tid; idx < 1024; idx += gridDim.x * 256) {
    const int r = idx & 3, l = (idx >> 2) & 63, ks = idx >> 8;
    const int g = l >> 4, c = l & 15;
    float va[2];
#pragma unroll
    for (int h = 0; h < 2; ++h) {
      const int khat = 2 * g + 16 * (r & 1) + 8 * h + (r >> 1);
      va[h] = W1g[(size_t)(32 * ks + khat) * CC + c];
    }
    uint32_t hi, mid; split2(va[0], va[1], hi, mid);
    W1F[(size_t)((ks * 2 + 0) * 64 + l) * 4 + r] = hi;
    W1F[(size_t)((ks * 2 + 1) * 64 + l) * 4 + r] = mid;
  }
}

// ---------------- Fused step kernel (MFMA) ----------------
// R12 configuration (session best, 203.6 us): one tile per block, 8192 blocks,
// dispatch order = spatial order (the locality mechanism — persistent loops
// destroy it: R13/R14 = 455MB FETCH, 2.2x slower).
// Thread map: wave w, lane l: px = 16w + (l&15), channel quarter g = l>>4
// -> perception thread == epilogue thread (ctr, fire in registers).
// Hs layout: [px][hid ^ swz(px)], swz(px) = (px&1) | ((px&6)<<2) -> 2-way
// banks on both write (GEMM1, b32) and read (GEMM2, b32) sides.
// XCD swizzle: blk = (bid&7)<<10 | bid>>3 -> each XCD owns one batch image;
// halo rows are XCD-local L2 hits (verified FETCH 39.7 -> 17.95 MB).
template <int APPLY_LIFE>
__global__ __launch_bounds__(256, 5)
void step_fused(const float* __restrict__ xin,
                const uint32_t* __restrict__ W0F,
                const uint32_t* __restrict__ W1F,
                const float* __restrict__ b0g,
                const float* __restrict__ aPrev,
                const unsigned char* __restrict__ mPrev,
                float* __restrict__ xn,
                float* __restrict__ alpha_out,
                unsigned char* __restrict__ prelife,
                uint32_t k0, uint32_t k1) {
  __shared__ uint32_t LDSU[LDS_DW];
  float* const LDSF = (float*)LDSU;

  const int t    = threadIdx.x;
  const int blk  = ((blockIdx.x & 7) << 10) | (blockIdx.x >> 3);  // XCD swizzle
  const int lane = t & 63;
  const int w    = __builtin_amdgcn_readfirstlane(t >> 6);  // wave 0..3
  const int g    = lane >> 4;
  const int c15  = lane & 15;

  // -- phase 0: issue slab-0 B-frags + bias early (latency under perception) --
  uint4 BH[2][2], BM[2][2];           // [ks parity][nl]
#pragma unroll
  for (int nl = 0; nl < 2; ++nl) {
    const int n = 2 * w + nl;
    BH[0][nl] = *(const uint4*)(W0F + (size_t)(((n * 3 + 0) * 2 + 0) * 64 + lane) * 4);
    BM[0][nl] = *(const uint4*)(W0F + (size_t)(((n * 3 + 0) * 2 + 1) * 64 + lane) * 4);
  }
  const float bv0 = b0g[16 * (2 * w + 0) + c15];
  const float bv1 = b0g[16 * (2 * w + 1) + c15];

  // Block geometry: 64 consecutive pixels = one row segment
  const int base_ = blk * MTILE;
  const int bi    = base_ >> 16;
  const int rc    = base_ & 0xFFFF;
  const int ic    = rc >> 8;
  const int jc0   = rc & 0xFF;        // multiple of 64

  // ---- inline life of previous step (compile-time gated) ----
  if constexpr (APPLY_LIFE) {
    const float* ap = aPrev + (size_t)bi * (HH * WW);
    for (int it = t; it < 340; it += 256) {        // alpha halo 5 x 68
      const int r = it / 68, c = it - r * 68;
      const int ii = ic - 2 + r, jj = jc0 - 2 + c;
      float v = 0.f;
      if ((unsigned)ii < (unsigned)HH && (unsigned)jj < (unsigned)WW)
        v = ap[ii * WW + jj];
      LDSF[ALPHA5_OFF + it] = v;
    }
    __syncthreads();
    if (t < 198) {                                  // life plane 3 x 66
      const int r = t / 66, xx = t - r * 66;
      const float* a0 = &LDSF[ALPHA5_OFF + r * 68 + xx];
      const float m0 = fmaxf(fmaxf(a0[0],   a0[1]),   a0[2]);
      const float m1 = fmaxf(fmaxf(a0[68],  a0[69]),  a0[70]);
      const float m2 = fmaxf(fmaxf(a0[136], a0[137]), a0[138]);
      const float mm = fmaxf(fmaxf(m0, m1), m2);
      const int ii = ic - 1 + r, jj = jc0 - 1 + xx;
      int pl = 0;
      if ((unsigned)ii < (unsigned)HH && (unsigned)jj < (unsigned)WW)
        pl = mPrev[(size_t)bi * (HH * WW) + ii * WW + jj];
      LDSF[LIFE_OFF + t] = (pl && mm > 0.1f) ? 1.0f : 0.0f;
    }
    __syncthreads();
  }

  // ---------------- perception: px = 16w + c15, quarter = g ----------------
  const int px  = 16 * w + c15;
  const int c4  = 4 * g;
  const int gpx = base_ + px;
  const int jc  = jc0 + px;

  const float DXW[3][3] = {{-0.125f, 0.0f, 0.125f},
                           {-0.25f,  0.0f, 0.25f },
                           {-0.125f, 0.0f, 0.125f}};
  const float DYW[3][3] = {{-0.125f, -0.25f, -0.125f},
                           { 0.0f,    0.0f,   0.0f  },
                           { 0.125f,  0.25f,  0.125f}};
  const float LPW[3][3] = {{0.125f, 0.25f, 0.125f},
                           {0.25f, -1.5f,  0.25f },
                           {0.125f, 0.25f, 0.125f}};
  const float L2W[3][3] = {{0.0f,   0.125f, 0.0f  },
                           {0.125f, -0.5f,  0.125f},
                           {0.0f,   0.125f, 0.0f  }};

  float ctr[4] = {0,0,0,0};
  float adx[4] = {0,0,0,0};
  float ady[4] = {0,0,0,0};
  float alp[4] = {0,0,0,0};
  float al2[4] = {0,0,0,0};
  float amax = 0.0f;

  const float* xb = xin + (size_t)bi * (HH * WW * CC);
#pragma unroll
  for (int di = -1; di <= 1; ++di) {
#pragma unroll
    for (int dj = -1; dj <= 1; ++dj) {
      const int ii = ic + di, jj = jc + dj;
      const bool ok = ((unsigned)ii < (unsigned)HH) && ((unsigned)jj < (unsigned)WW);
      float4 p = make_float4(0.f, 0.f, 0.f, 0.f);
      if (ok) p = *(const float4*)(xb + ((size_t)(ii * WW + jj) * CC + c4));
      if constexpr (APPLY_LIFE) {
        const float lf = LDSF[LIFE_OFF + (di + 1) * 66 + (px + dj + 1)];
        p.x *= lf; p.y *= lf; p.z *= lf; p.w *= lf;
      }
      const float wdx = DXW[di+1][dj+1], wdy = DYW[di+1][dj+1];
      const float wlp = LPW[di+1][dj+1], wl2 = L2W[di+1][dj+1];
      const float pv[4] = {p.x, p.y, p.z, p.w};
#pragma unroll
      for (int q = 0; q < 4; ++q) {
        if (di == 0 && dj == 0) ctr[q] = pv[q];
        if (wdx != 0.f) adx[q] = fmaf(pv[q], wdx, adx[q]);
        if (wdy != 0.f) ady[q] = fmaf(pv[q], wdy, ady[q]);
        if (wlp != 0.f) alp[q] = fmaf(pv[q], wlp, alp[q]);
        if (wl2 != 0.f) al2[q] = fmaf(pv[q], wl2, al2[q]);
      }
      if (g == 0) amax = fmaxf(amax, p.w);   // channel 3 lives in quarter 0
    }
  }

  // fire: wave 0 computes all 64 pixels' threefry once (waves 1-3 skip the
  // whole ~100-instr chain via execz). Slot t holds fire for pixel base_+t.
  if (t < 64) {
    uint32_t lo, hi2;
    threefry2x32(k0, k1, 0u, (uint32_t)(base_ + t), lo, hi2);
    const uint32_t bits = lo ^ hi2;
    const float u = __uint_as_float((bits >> 9) | 0x3f800000u) - 1.0f;
    LDSF[FIRE_OFF + t] = (u > 0.5f) ? 1.0f : 0.0f;
  }

  // Ypk writes: packed f16x2 pairs, kk = 8*grp + 2g (+1). stride 52.
  {
    const int q2 = g << 1;
#define WRYPK(grp, A) do { \
    uint32_t h0_, m0_, h1_, m1_; \
    split2(A[0], A[1], h0_, m0_); split2(A[2], A[3], h1_, m1_); \
    const int kk_ = 8 * (grp) + q2; \
    *(uint2*)&LDSU[YPK_HI  + px * 52 + kk_] = make_uint2(h0_, h1_); \
    *(uint2*)&LDSU[YPK_MID + px * 52 + kk_] = make_uint2(m0_, m1_); \
  } while (0)
    WRYPK(0, ctr); WRYPK(1, adx); WRYPK(2, ady); WRYPK(3, alp); WRYPK(4, al2);
#undef WRYPK
  }
  // zero K-pad rows kk 40..47 (k 80..95), both planes
#pragma unroll
  for (int j = 0; j < 4; ++j) {
    const int pos = t * 4 + j;
    const int plane = pos >> 9, rem = pos & 511;
    LDSU[plane * 3328 + (rem >> 3) * 52 + 40 + (rem & 7)] = 0u;
  }
  if (g == 0) prelife[gpx] = (amax > 0.1f) ? 1 : 0;

  __syncthreads();

  // own fire into a register BEFORE epoch 2 (Hs) overlays the staging area.
  // The empty asm pins the loaded value here: the ds_read provably completes
  // between the staging barrier and the pre-Hs barrier (cannot sink to use).
  float fire01 = LDSF[FIRE_OFF + px];
  asm volatile("" : "+v"(fire01));

  // ------- GEMM1: D[px][hid] = Y @ W0, split-fp16 3-product MFMA ----------
  f4 C1[4][2];
#pragma unroll
  for (int m = 0; m < 4; ++m) {
    C1[m][0] = (f4){bv0, bv0, bv0, bv0};
    C1[m][1] = (f4){bv1, bv1, bv1, bv1};
  }

#define LOADB(par, kss) do { \
  _Pragma("unroll") for (int nl_ = 0; nl_ < 2; ++nl_) { \
    const int n_ = 2 * w + nl_; \
    BH[par][nl_] = *(const uint4*)(W0F + (size_t)(((n_ * 3 + (kss)) * 2 + 0) * 64 + lane) * 4); \
    BM[par][nl_] = *(const uint4*)(W0F + (size_t)(((n_ * 3 + (kss)) * 2 + 1) * 64 + lane) * 4); \
  } } while (0)

  const int abase = c15 * 52 + 4 * g;
#pragma unroll
  for (int ks = 0; ks < 3; ++ks) {
    if (ks == 0) LOADB(1, 1);
    if (ks == 1) LOADB(0, 2);
    const int cur = ks & 1;
    __builtin_amdgcn_s_setprio(1);      // favor MFMA-issuing wave on the CU
#pragma unroll
    for (int m = 0; m < 4; ++m) {
      const uint4 uh = *(const uint4*)&LDSU[YPK_HI  + abase + m * 832 + 16 * ks];
      const uint4 um = *(const uint4*)&LDSU[YPK_MID + abase + m * 832 + 16 * ks];
      const h8 ah = __builtin_bit_cast(h8, uh);
      const h8 am = __builtin_bit_cast(h8, um);
#pragma unroll
      for (int nl = 0; nl < 2; ++nl) {
        const h8 bh = __builtin_bit_cast(h8, BH[cur][nl]);
        const h8 bm = __builtin_bit_cast(h8, BM[cur][nl]);
        C1[m][nl] = __builtin_amdgcn_mfma_f32_16x16x32_f16(ah, bh, C1[m][nl], 0, 0, 0);
        C1[m][nl] = __builtin_amdgcn_mfma_f32_16x16x32_f16(am, bh, C1[m][nl], 0, 0, 0);
        C1[m][nl] = __builtin_amdgcn_mfma_f32_16x16x32_f16(ah, bm, C1[m][nl], 0, 0, 0);
      }
    }
    __builtin_amdgcn_s_setprio(0);
  }
#undef LOADB

  __syncthreads();   // all Ypk/FIRE reads done before Hs overwrites the union

  // relu + h store, transposed+swizzled: Hs[px_w][hid ^ swz(px_w)]
  // swz(px_w) = (j&1) | ((j&2)<<2) | ((g&1)<<4) for px_w = 16m+4g+j
  {
    const int sg = (g & 1) << 4;
    const int hid0 = 32 * w + c15;
    const int hid1 = hid0 + 16;
    const int hx00 = hid0 ^ sg,       hx01 = hid0 ^ (sg | 1);
    const int hx02 = hid0 ^ (sg | 8), hx03 = hid0 ^ (sg | 9);
    const int hx10 = hid1 ^ sg,       hx11 = hid1 ^ (sg | 1);
    const int hx12 = hid1 ^ (sg | 8), hx13 = hid1 ^ (sg | 9);
#pragma unroll
    for (int m = 0; m < 4; ++m) {
      const int rowb = (16 * m + 4 * g) * 128;
      {
        f4 hv = C1[m][0];
        LDSF[rowb +   0 + hx00] = fmaxf(hv.x, 0.f);
        LDSF[rowb + 128 + hx01] = fmaxf(hv.y, 0.f);
        LDSF[rowb + 256 + hx02] = fmaxf(hv.z, 0.f);
        LDSF[rowb + 384 + hx03] = fmaxf(hv.w, 0.f);
      }
      {
        f4 hv = C1[m][1];
        LDSF[rowb +   0 + hx10] = fmaxf(hv.x, 0.f);
        LDSF[rowb + 128 + hx11] = fmaxf(hv.y, 0.f);
        LDSF[rowb + 256 + hx12] = fmaxf(hv.z, 0.f);
        LDSF[rowb + 384 + hx13] = fmaxf(hv.w, 0.f);
      }
    }
  }

  // W1^T A-frags (latency covered by barrier)
  uint4 W1H[4], W1M[4];
#pragma unroll
  for (int ks = 0; ks < 4; ++ks) {
    W1H[ks] = *(const uint4*)(W1F + (size_t)((ks * 2 + 0) * 64 + lane) * 4);
    W1M[ks] = *(const uint4*)(W1F + (size_t)((ks * 2 + 1) * 64 + lane) * 4);
  }

  __syncthreads();

  // ------- GEMM2: D[ch][px] = W1^T @ h^T (wave w: px-tile w) ---------------
  // Read h[32ks + khat][px] at px*128 + 2g + 32ks + (K0h ^ swz(px)),
  // khat = 2g + K0h, K0h = 16(r&1) + 8h + (r>>1); swz bits {0,3,4} disjoint
  // from 2g bits {1,2} and 32ks bits {5,6}.
  f4 C2 = (f4){0.f, 0.f, 0.f, 0.f};
  {
    const int swzr  = (c15 & 1) | ((c15 & 6) << 2);
    const int hbase = px * 128 + 2 * g;
    int ka[4], kb[4];
#pragma unroll
    for (int r = 0; r < 4; ++r) {
      const int K0 = 16 * (r & 1) + (r >> 1);
      ka[r] = K0 ^ swzr;
      kb[r] = (K0 + 8) ^ swzr;
    }
#pragma unroll
    for (int ks = 0; ks < 4; ++ks) {
      uint32_t ph[4], pm[4];
#pragma unroll
      for (int r = 0; r < 4; ++r) {
        const float a = LDSF[hbase + 32 * ks + ka[r]];
        const float b = LDSF[hbase + 32 * ks + kb[r]];
        split2(a, b, ph[r], pm[r]);
      }
      const uint4 uh = make_uint4(ph[0], ph[1], ph[2], ph[3]);
      const uint4 um = make_uint4(pm[0], pm[1], pm[2], pm[3]);
      const h8 bh = __builtin_bit_cast(h8, uh);
      const h8 bm = __builtin_bit_cast(h8, um);
      const h8 ah = __builtin_bit_cast(h8, W1H[ks]);
      const h8 am = __builtin_bit_cast(h8, W1M[ks]);
      __builtin_amdgcn_s_setprio(1);
      C2 = __builtin_amdgcn_mfma_f32_16x16x32_f16(ah, bh, C2, 0, 0, 0);
      C2 = __builtin_amdgcn_mfma_f32_16x16x32_f16(am, bh, C2, 0, 0, 0);
      C2 = __builtin_amdgcn_mfma_f32_16x16x32_f16(ah, bm, C2, 0, 0, 0);
      __builtin_amdgcn_s_setprio(0);
    }
  }

  // ------- epilogue: all in registers (ctr, fire01 are this thread's own) --
  {
    f4 xv;
    xv.x = fmaf(C2.x, fire01, ctr[0]);
    xv.y = fmaf(C2.y, fire01, ctr[1]);
    xv.z = fmaf(C2.z, fire01, ctr[2]);
    xv.w = fmaf(C2.w, fire01, ctr[3]);
    *(f4*)&xn[(size_t)gpx * CC + c4] = xv;
    if (g == 0) alpha_out[gpx] = xv.w;   // channel 3
  }
}

// ---------------- Kernel B: final life mask, write-only-dead, in-place -----
__global__ __launch_bounds__(256)
void life_final(float* __restrict__ out,
                const float* __restrict__ alpha,
                const unsigned char* __restrict__ prelife) {
  // XCD swizzle (2048 blocks): XCD k gets one batch image's quarter-planes
  const int bswz = ((blockIdx.x & 7) << 8) | (blockIdx.x >> 3);
  const int idx = bswz * 256 + threadIdx.x;
  const int b  = idx >> 16;
  const int ij = idx & 0xFFFF;
  const int i  = ij >> 8;
  const int j  = ij & 0xFF;

  const float* ab = alpha + (size_t)b * (HH * WW);
  float amax = 0.0f;
#pragma unroll
  for (int di = -1; di <= 1; ++di) {
    const int ii = i + di;
    if ((unsigned)ii >= (unsigned)HH) continue;
#pragma unroll
    for (int dj = -1; dj <= 1; ++dj) {
      const int jj = j + dj;
      if ((unsigned)jj >= (unsigned)WW) continue;
      amax = fmaxf(amax, ab[(size_t)ii * WW + jj]);
    }
  }
  const bool life = (prelife[idx] != 0) && (amax > 0.1f);
  if (!life) {
    const float4 z = make_float4(0.0f, 0.0f, 0.0f, 0.0f);
    float4* dst = (float4*)(out + (size_t)idx * CC);
    dst[0] = z; dst[1] = z; dst[2] = z; dst[3] = z;
  }
}

// ---------------- Host launcher ----------------
extern "C" void kernel_launch(void* const* d_in, const int* in_sizes, int n_in,
                              void* d_out, int out_size, void* d_ws, size_t ws_size,
                              hipStream_t stream) {
  (void)in_sizes; (void)n_in; (void)out_size; (void)ws_size;
  const float* x  = (const float*)d_in[0];
  const float* W0 = (const float*)d_in[1];
  const float* b0 = (const float*)d_in[2];
  const float* W1 = (const float*)d_in[3];
  float* out = (float*)d_out;

  // Workspace: xn (32MB) | alphaA (2MB) | alphaB (2MB) | maskA | maskB | W0F | W1F
  float* xn = (float*)d_ws;
  float* alphaA = xn + (size_t)NPIX * CC;
  float* alphaB = alphaA + NPIX;
  unsigned char* maskA = (unsigned char*)(alphaB + NPIX);
  unsigned char* maskB = maskA + NPIX;
  uint32_t* W0F = (uint32_t*)(maskB + NPIX);
  uint32_t* W1F = W0F + 12288;

  prep_frags<<<128, 256, 0, stream>>>(W0, W1, W0F, W1F);

  uint32_t fk0, fk1;
  // step 0: raw input (no life), unmasked result -> xn, alpha/mask -> A
  threefry2x32(0u, 42u, 0u, 0u, fk0, fk1);
  step_fused<0><<<NBLK, 256, 0, stream>>>(x, W0F, W1F, b0, nullptr, nullptr,
                                          xn, alphaA, maskA, fk0, fk1);
  // step 1: reads UNMASKED xn, applies step-0 life inline (alphaA/maskA)
  threefry2x32(0u, 42u, 0u, 1u, fk0, fk1);
  step_fused<1><<<NBLK, 256, 0, stream>>>(xn, W0F, W1F, b0, alphaA, maskA,
                                          out, alphaB, maskB, fk0, fk1);
  // final masking: zero dead pixels of out in place
  life_final<<<NPIX / 256, 256, 0, stream>>>(out, alphaB, maskB);
}